// Round 4
// baseline (342.303 us; speedup 1.0000x reference)
//
#include <hip/hip_runtime.h>

#define NB 512
#define ND 32
#define NH 256
#define NSTEPS 8

typedef __attribute__((ext_vector_type(8))) short short8;
typedef __attribute__((ext_vector_type(4))) short short4v;
typedef __attribute__((ext_vector_type(4))) float f32x4;

__device__ __constant__ float Atab[6][5] = {
    {0.f, 0.f, 0.f, 0.f, 0.f},
    {0.2f, 0.f, 0.f, 0.f, 0.f},
    {3.f/40.f, 9.f/40.f, 0.f, 0.f, 0.f},
    {44.f/45.f, -56.f/15.f, 32.f/9.f, 0.f, 0.f},
    {19372.f/6561.f, -25360.f/2187.f, 64448.f/6561.f, -212.f/729.f, 0.f},
    {9017.f/3168.f, -355.f/33.f, 46732.f/5247.f, 49.f/176.f, -5103.f/18656.f}
};
__device__ __constant__ float Btab[6] = {
    35.f/384.f, 0.f, 500.f/1113.f, 125.f/192.f, -2187.f/6784.f, 11.f/84.f
};
__device__ __constant__ float Ctab[6] = {0.f, 0.2f, 0.3f, 0.8f, 8.f/9.f, 1.f};

static __device__ __forceinline__ short f2bf(float f){
    __bf16 h = (__bf16)f;
    return __builtin_bit_cast(short, h);
}
static __device__ __forceinline__ float bf_lo(unsigned p){
    return __builtin_bit_cast(float, p << 16);
}
static __device__ __forceinline__ float bf_hi(unsigned p){
    return __builtin_bit_cast(float, p & 0xffff0000u);
}
static __device__ __forceinline__ float fast_tanh(float x){
    float e = __expf(2.f * x);
    return 1.f - 2.f / (e + 1.f);
}

// XOR-swizzled LDS addressing: row stride 512B, byte ^= (row&7)<<4.
#define SWZ(base, row, byte) ((base) + ((row) << 9) + ((byte) ^ (((row) & 7) << 4)))

// ---- prep: fragment-ordered bf16 W3 into ws ----
// frag(mt,kk), lane l: short8 of W3[kk*32+g*8+e][mt*16+c], at ws[(mt*8+kk)*64+l]
extern "C" __global__ void prep_kernel(const float* __restrict__ W3,
                                       short8* __restrict__ ws)
{
    const int tid = threadIdx.x;
    #pragma unroll
    for (int r = 0; r < 4; ++r) {
        const int idx = r*256 + tid;          // 0..1023
        const int l  = idx & 63;
        const int kk = (idx >> 6) & 7;
        const int mt = idx >> 9;
        const int g = (l >> 4) & 3, c = l & 15;
        short8 v;
        #pragma unroll
        for (int e = 0; e < 8; ++e)
            v[e] = f2bf(W3[(kk*32 + g*8 + e)*ND + mt*16 + c]);
        ws[idx] = v;
    }
}

// One block per batch element; 4 waves (256 threads).
// T^T GEMM: M=j(256, 4 Mtiles/wave), N=i(33: 32 tangent + h1 col), K=256.
// W2 fragments register-resident; W3 fragments streamed from ws (L2).
extern "C" __global__ void __launch_bounds__(256, 1)
node_kernel(const float* __restrict__ x_in,
            const float* __restrict__ W1, const float* __restrict__ b1,
            const float* __restrict__ W2, const float* __restrict__ b2,
            const float* __restrict__ W3, const float* __restrict__ b3,
            const short8* __restrict__ w3ws,
            float* __restrict__ out)
{
    __shared__ __align__(16) short LA[33*256];   // A^T rows 0..31 + row32(h1/h2); reused as Ts^T
    __shared__ __align__(16) float h2pre_s[NH];
    __shared__ __align__(16) float s2_s[NH];
    __shared__ __align__(16) float xs_s[ND];
    __shared__ __align__(16) float xc_s[ND];
    __shared__ __align__(16) float ksb[6][ND];
    __shared__ float red[4][3];

    const int bid = blockIdx.x;
    const int tid = threadIdx.x;
    const int w = tid >> 6;        // wave id
    const int l = tid & 63;        // lane
    const int g = (tid >> 4) & 3;  // lane group
    const int c = tid & 15;        // lane&15

    char* LAc = (char*)LA;
    const int swc = (c & 7) << 4;  // read-side swizzle

    // ---- one-time: W2 fragments into registers ----
    // frag (m,kk): value W2[kk*32+g*8+e][w*64+m*16+c]
    short8 w2f[4][8];
    #pragma unroll
    for (int m = 0; m < 4; ++m) {
        const int j = w*64 + m*16 + c;
        #pragma unroll
        for (int kk = 0; kk < 8; ++kk) {
            const int k0 = kk*32 + g*8;
            short8 f;
            #pragma unroll
            for (int e = 0; e < 8; ++e) f[e] = f2bf(W2[(k0+e)*NH + j]);
            w2f[m][kk] = f;
        }
    }
    // ---- one-time: W1 column tid packed bf16 + biases ----
    unsigned w1p[16];
    float w1t, b1u, b2u;
    {
        #pragma unroll
        for (int q = 0; q < 16; ++q) {
            unsigned lo = (unsigned)(unsigned short)f2bf(W1[(2*q)*NH + tid]);
            unsigned hi = (unsigned)(unsigned short)f2bf(W1[(2*q+1)*NH + tid]);
            w1p[q] = lo | (hi << 16);
        }
        w1t = W1[32*NH + tid];
        b1u = b1[tid];
        b2u = b2[tid];
    }
    // ---- one-time: b3 quads for the vf lanes (wave3, c==0) ----
    f32x4 b3a = (f32x4){0,0,0,0}, b3b = (f32x4){0,0,0,0};
    if (w == 3 && c == 0) {
        b3a = *(const f32x4*)(b3 + g*4);
        b3b = *(const f32x4*)(b3 + 16 + g*4);
    }
    // ---- J-phase tile assignment ----
    // w0:(0,0)+(1,1) [diag], w1:(0,1), w2:(1,0), w3:(0,2)+(1,2) [vf]
    const int mtA = (w == 2) ? 1 : 0;
    const int ntA = (w == 0) ? 0 : (w == 1) ? 1 : (w == 2) ? 0 : 2;
    const bool twoT = (w == 0) || (w == 3);
    const int ntB = (w == 0) ? 1 : 2;   // mtB == 1 always

    // ---- init state (wave3-private) ----
    if (w == 3 && l < ND) {
        const float xv = x_in[bid*ND + l];
        xc_s[l] = xv;
        xs_s[l] = xv;
    }

    const float dt = 0.125f;
    float fr_acc = 0.f, ld_acc = 0.f, vf_acc = 0.f;
    const short8 zfrag = {0,0,0,0,0,0,0,0};

    for (int n = 0; n < NSTEPS; ++n) {
        const float t0 = (float)n * dt;
        for (int sg = 0; sg < 6; ++sg) {
            __syncthreads();   // Bstart: xs ready; prev J-phase LTs reads done
            const float t_eff = 1.0f - (t0 + Ctab[sg]*dt);

            // ---- layer 1 + A-column build (thread = hidden unit tid, in-reg) ----
            {
                float pre = b1u + t_eff * w1t;
                #pragma unroll
                for (int q = 0; q < 8; ++q) {
                    f32x4 xq = *(const f32x4*)&xs_s[q*4];   // broadcast reads
                    unsigned p0 = w1p[2*q], p1 = w1p[2*q+1];
                    pre += xq[0]*bf_lo(p0) + xq[1]*bf_hi(p0)
                         + xq[2]*bf_lo(p1) + xq[3]*bf_hi(p1);
                }
                const float h1 = fast_tanh(pre);
                const float s1 = 1.f - h1*h1;
                #pragma unroll
                for (int q = 0; q < 16; ++q) {
                    unsigned p = w1p[q];
                    *(short*)SWZ(LAc, 2*q,   2*tid) = f2bf(bf_lo(p)*s1);
                    *(short*)SWZ(LAc, 2*q+1, 2*tid) = f2bf(bf_hi(p)*s1);
                }
                ((short*)LA)[32*256 + tid] = f2bf(h1);  // row32 (swz==0)
            }
            __syncthreads();   // B3: A ready

            // ---- T^T GEMM: j = w*64+m*16+g*4+r, i = nt*16+c ----
            f32x4 acc[4][3];
            #pragma unroll
            for (int m = 0; m < 4; ++m)
                #pragma unroll
                for (int q = 0; q < 3; ++q) acc[m][q] = (f32x4){0.f,0.f,0.f,0.f};
            #pragma unroll
            for (int kk = 0; kk < 8; ++kk) {
                const int bo = kk*64 + g*16;
                short8 fA0 = *(const short8*)(LAc + (( 0 + c) << 9) + (bo ^ swc));
                short8 fA1 = *(const short8*)(LAc + ((16 + c) << 9) + (bo ^ swc));
                short8 fA2 = zfrag;                       // i=32 col: h1 only at c==0
                if (c == 0) fA2 = *(const short8*)(LAc + (32 << 9) + bo);
                #pragma unroll
                for (int m = 0; m < 4; ++m) {
                    acc[m][0] = __builtin_amdgcn_mfma_f32_16x16x32_bf16(w2f[m][kk], fA0, acc[m][0], 0,0,0);
                    acc[m][1] = __builtin_amdgcn_mfma_f32_16x16x32_bf16(w2f[m][kk], fA1, acc[m][1], 0,0,0);
                    acc[m][2] = __builtin_amdgcn_mfma_f32_16x16x32_bf16(w2f[m][kk], fA2, acc[m][2], 0,0,0);
                }
            }
            // h2_pre exchange (own-wave LDS) + activation
            if (c == 0) {
                #pragma unroll
                for (int m = 0; m < 4; ++m)
                    *(f32x4*)&h2pre_s[w*64 + m*16 + g*4] = acc[m][2];
            }
            const float h2 = fast_tanh(h2pre_s[tid] + b2u);
            s2_s[tid] = 1.f - h2*h2;
            __syncthreads();   // B4: all A reads done -> LA writable as Ts

            ((short*)LA)[32*256 + tid] = f2bf(h2);       // row32 := h2
            // ---- Ts^T store: LA[i][j] = T^T[j][i]*s2[j] ----
            #pragma unroll
            for (int m = 0; m < 4; ++m) {
                const int j0 = w*64 + m*16 + g*4;
                f32x4 s2q = *(const f32x4*)&s2_s[j0];    // broadcast (own wave)
                #pragma unroll
                for (int q = 0; q < 2; ++q) {
                    f32x4 v = acc[m][q] * s2q;
                    short4v p;
                    p[0] = f2bf(v[0]); p[1] = f2bf(v[1]); p[2] = f2bf(v[2]); p[3] = f2bf(v[3]);
                    *(short4v*)SWZ(LAc, q*16 + c, 2*j0) = p;
                }
            }
            // ---- issue W3 fragment loads (set A) before the barrier ----
            short8 w3A[8];
            #pragma unroll
            for (int kk = 0; kk < 8; ++kk) w3A[kk] = w3ws[(mtA*8 + kk)*64 + l];
            __syncthreads();   // B5: Ts ready
            short8 w3B[8];
            if (twoT) {
                #pragma unroll
                for (int kk = 0; kk < 8; ++kk) w3B[kk] = w3ws[(8 + kk)*64 + l];  // mtB=1
            }

            // ---- J^T GEMM ----
            f32x4 ja = (f32x4){0,0,0,0}, jb = (f32x4){0,0,0,0};
            #pragma unroll
            for (int kk = 0; kk < 8; ++kk) {
                const int bo = kk*64 + g*16;
                short8 bbA;
                if (ntA == 2) {                           // wave3: h2 column
                    bbA = zfrag;
                    if (c == 0) bbA = *(const short8*)(LAc + (32 << 9) + bo);
                } else {
                    bbA = *(const short8*)(LAc + ((ntA*16 + c) << 9) + (bo ^ swc));
                }
                ja = __builtin_amdgcn_mfma_f32_16x16x32_bf16(w3A[kk], bbA, ja, 0,0,0);
            }
            if (twoT) {
                #pragma unroll
                for (int kk = 0; kk < 8; ++kk) {
                    const int bo = kk*64 + g*16;
                    short8 bbB;
                    if (ntB == 2) {                       // wave3
                        bbB = zfrag;
                        if (c == 0) bbB = *(const short8*)(LAc + (32 << 9) + bo);
                    } else {                              // wave0: nt=1
                        bbB = *(const short8*)(LAc + ((16 + c) << 9) + (bo ^ swc));
                    }
                    jb = __builtin_amdgcn_mfma_f32_16x16x32_bf16(w3B[kk], bbB, jb, 0,0,0);
                }
            }

            // ---- per-thread weighted accumulation ----
            const float wB = dt * Btab[sg];
            if (w == 3) {
                if (c == 0) {
                    f32x4 dxa, dxb;
                    dxa[0] = -(ja[0]+b3a[0]); dxa[1] = -(ja[1]+b3a[1]);
                    dxa[2] = -(ja[2]+b3a[2]); dxa[3] = -(ja[3]+b3a[3]);
                    dxb[0] = -(jb[0]+b3b[0]); dxb[1] = -(jb[1]+b3b[1]);
                    dxb[2] = -(jb[2]+b3b[2]); dxb[3] = -(jb[3]+b3b[3]);
                    *(f32x4*)&ksb[sg][g*4]      = dxa;
                    *(f32x4*)&ksb[sg][16 + g*4] = dxb;
                    vf_acc += wB * (dxa[0]*dxa[0]+dxa[1]*dxa[1]+dxa[2]*dxa[2]+dxa[3]*dxa[3]
                                  + dxb[0]*dxb[0]+dxb[1]*dxb[1]+dxb[2]*dxb[2]+dxb[3]*dxb[3]);
                }
                // ---- wave3-private state update (same-wave LDS, in-order) ----
                if (l < ND) {
                    if (sg < 5) {
                        float v = xc_s[l];
                        for (int q = 0; q <= sg; ++q) v += dt * Atab[sg+1][q] * ksb[q][l];
                        xs_s[l] = v;
                    } else {
                        float v = xc_s[l];
                        #pragma unroll
                        for (int q = 0; q < 6; ++q) v += dt * Btab[q] * ksb[q][l];
                        xc_s[l] = v;
                        xs_s[l] = v;
                    }
                }
            } else {
                fr_acc += wB * (ja[0]*ja[0]+ja[1]*ja[1]+ja[2]*ja[2]+ja[3]*ja[3]);
                if (twoT)   // wave0 second tile (1,1)
                    fr_acc += wB * (jb[0]*jb[0]+jb[1]*jb[1]+jb[2]*jb[2]+jb[3]*jb[3]);
                if (w == 0) {
                    const int dd = c - g*4;
                    if (dd >= 0 && dd < 4) {
                        float da = (dd==0)?ja[0]:(dd==1)?ja[1]:(dd==2)?ja[2]:ja[3];
                        float db = (dd==0)?jb[0]:(dd==1)?jb[1]:(dd==2)?jb[2]:jb[3];
                        ld_acc -= wB * (da + db);
                    }
                }
            }
        }
    }

    // ---- final reduction of the three integrals ----
    float fr = fr_acc, ld = ld_acc, vf = vf_acc;
    #pragma unroll
    for (int off = 32; off > 0; off >>= 1) {
        fr += __shfl_down(fr, off, 64);
        ld += __shfl_down(ld, off, 64);
        vf += __shfl_down(vf, off, 64);
    }
    if (l == 0) { red[w][0] = fr; red[w][1] = ld; red[w][2] = vf; }
    __syncthreads();
    if (tid == 0) {
        float a = 0.f, b = 0.f, cq = 0.f;
        #pragma unroll
        for (int q = 0; q < 4; ++q) { a += red[q][0]; b += red[q][1]; cq += red[q][2]; }
        out[bid*35 + 32] = b;    // log_det = -∫tr
        out[bid*35 + 33] = cq;   // ∫|dxdt|^2
        out[bid*35 + 34] = a;    // ∫sum(J*J)
    }
    if (w == 3 && l < ND) out[bid*35 + l] = xc_s[l];
}

extern "C" void kernel_launch(void* const* d_in, const int* in_sizes, int n_in,
                              void* d_out, int out_size, void* d_ws, size_t ws_size,
                              hipStream_t stream) {
    const float* x  = (const float*)d_in[0];
    const float* W1 = (const float*)d_in[1];
    const float* b1 = (const float*)d_in[2];
    const float* W2 = (const float*)d_in[3];
    const float* b2 = (const float*)d_in[4];
    const float* W3 = (const float*)d_in[5];
    const float* b3 = (const float*)d_in[6];
    float* outp = (float*)d_out;
    hipLaunchKernelGGL(prep_kernel, dim3(1), dim3(256), 0, stream,
                       W3, (short8*)d_ws);
    hipLaunchKernelGGL(node_kernel, dim3(NB), dim3(256), 0, stream,
                       x, W1, b1, W2, b2, W3, b3, (const short8*)d_ws, outp);
}

// Round 5
// 270.623 us; speedup vs baseline: 1.2649x; 1.2649x over previous
//
#include <hip/hip_runtime.h>

#define NB 512
#define ND 32
#define NH 256
#define NSTEPS 8

typedef __attribute__((ext_vector_type(8))) short short8;
typedef __attribute__((ext_vector_type(4))) short short4v;
typedef __attribute__((ext_vector_type(4))) float f32x4;

__device__ __constant__ float Atab[6][5] = {
    {0.f, 0.f, 0.f, 0.f, 0.f},
    {0.2f, 0.f, 0.f, 0.f, 0.f},
    {3.f/40.f, 9.f/40.f, 0.f, 0.f, 0.f},
    {44.f/45.f, -56.f/15.f, 32.f/9.f, 0.f, 0.f},
    {19372.f/6561.f, -25360.f/2187.f, 64448.f/6561.f, -212.f/729.f, 0.f},
    {9017.f/3168.f, -355.f/33.f, 46732.f/5247.f, 49.f/176.f, -5103.f/18656.f}
};
__device__ __constant__ float Btab[6] = {
    35.f/384.f, 0.f, 500.f/1113.f, 125.f/192.f, -2187.f/6784.f, 11.f/84.f
};
__device__ __constant__ float Ctab[6] = {0.f, 0.2f, 0.3f, 0.8f, 8.f/9.f, 1.f};

static __device__ __forceinline__ short f2bf(float f){
    __bf16 h = (__bf16)f;
    return __builtin_bit_cast(short, h);
}
static __device__ __forceinline__ float bf_lo(unsigned p){
    return __builtin_bit_cast(float, p << 16);
}
static __device__ __forceinline__ float bf_hi(unsigned p){
    return __builtin_bit_cast(float, p & 0xffff0000u);
}
static __device__ __forceinline__ float fast_tanh(float x){
    float e = __expf(2.f * x);
    return 1.f - 2.f / (e + 1.f);
}

// XOR-swizzled LDS addressing: row stride 512B, byte ^= (row&7)<<4.
#define SWZ(base, row, byte) ((base) + ((row) << 9) + ((byte) ^ (((row) & 7) << 4)))

// ---- prep: fragment-ordered bf16 W3 into ws ----
// frag(mt,kk), lane l: short8 of W3[kk*32+g*8+e][mt*16+c], at ws[(mt*8+kk)*64+l]
extern "C" __global__ void prep_kernel(const float* __restrict__ W3,
                                       short8* __restrict__ ws)
{
    const int tid = threadIdx.x;
    #pragma unroll
    for (int r = 0; r < 4; ++r) {
        const int idx = r*256 + tid;          // 0..1023
        const int l  = idx & 63;
        const int kk = (idx >> 6) & 7;
        const int mt = idx >> 9;
        const int g = (l >> 4) & 3, c = l & 15;
        short8 v;
        #pragma unroll
        for (int e = 0; e < 8; ++e)
            v[e] = f2bf(W3[(kk*32 + g*8 + e)*ND + mt*16 + c]);
        ws[idx] = v;
    }
}

// One block per batch element; 4 waves (256 threads); target 2 blocks/CU.
// T^T GEMM: M=j(256, 4 Mtiles/wave), N=i(33: 32 tangent + h1 col), K=256.
// W2 fragments register-resident; W3 fragments in LDS; per-wave private ODE state.
extern "C" __global__ void __launch_bounds__(256, 2)
node_kernel(const float* __restrict__ x_in,
            const float* __restrict__ W1, const float* __restrict__ b1,
            const float* __restrict__ W2, const float* __restrict__ b2,
            const float* __restrict__ W3, const float* __restrict__ b3,
            const short8* __restrict__ w3ws,
            float* __restrict__ out)
{
    __shared__ __align__(16) short LAA[33*256];   // A^T rows 0..31 + row32 = h1 (swizzled)
    __shared__ __align__(16) short LTs[33*256];   // Ts^T rows 0..31 + row32 = h2 (swizzled)
    __shared__ __align__(16) short8 W3L[16*64];   // fragment-ordered W3 (16 KB)
    __shared__ __align__(16) float h2pre_s[NH];
    __shared__ __align__(16) float s2_s[NH];
    __shared__ __align__(16) float xs_s[4][ND];   // per-wave private
    __shared__ __align__(16) float xc_s[4][ND];   // per-wave private
    __shared__ __align__(16) float ksb[4][6][ND]; // per-wave private
    __shared__ float red[4][3];

    const int bid = blockIdx.x;
    const int tid = threadIdx.x;
    const int w = tid >> 6;        // wave id
    const int l = tid & 63;        // lane
    const int g = (tid >> 4) & 3;  // lane group
    const int c = tid & 15;        // lane&15

    char* LAc = (char*)LAA;
    char* LTc = (char*)LTs;
    const int swc = (c & 7) << 4;  // read-side swizzle

    // ---- one-time: W2 fragments into registers ----
    // frag (m,kk): value W2[kk*32+g*8+e][w*64+m*16+c]
    short8 w2f[4][8];
    #pragma unroll
    for (int m = 0; m < 4; ++m) {
        const int j = w*64 + m*16 + c;
        #pragma unroll
        for (int kk = 0; kk < 8; ++kk) {
            const int k0 = kk*32 + g*8;
            short8 f;
            #pragma unroll
            for (int e = 0; e < 8; ++e) f[e] = f2bf(W2[(k0+e)*NH + j]);
            w2f[m][kk] = f;
        }
    }
    // ---- one-time: W1 column tid packed bf16 + biases ----
    unsigned w1p[16];
    float w1t, b1u, b2u;
    {
        #pragma unroll
        for (int q = 0; q < 16; ++q) {
            unsigned lo = (unsigned)(unsigned short)f2bf(W1[(2*q)*NH + tid]);
            unsigned hi = (unsigned)(unsigned short)f2bf(W1[(2*q+1)*NH + tid]);
            w1p[q] = lo | (hi << 16);
        }
        w1t = W1[32*NH + tid];
        b1u = b1[tid];
        b2u = b2[tid];
    }
    // ---- one-time: b3 quads (used at c==0 lanes) ----
    const f32x4 b3a = *(const f32x4*)(b3 + g*4);
    const f32x4 b3b = *(const f32x4*)(b3 + 16 + g*4);
    // ---- one-time: W3 fragments global->LDS (coalesced b128) ----
    #pragma unroll
    for (int r = 0; r < 4; ++r) W3L[r*256 + tid] = w3ws[r*256 + tid];
    // ---- J-phase: each wave owns one J tile ----
    const int mtJ = w >> 1, ntJ = w & 1;

    // ---- init per-wave ODE state ----
    if (l < ND) {
        const float xv = x_in[bid*ND + l];
        xc_s[w][l] = xv;
        xs_s[w][l] = xv;
    }
    __syncthreads();

    const float dt = 0.125f;
    float fr_acc = 0.f, ld_acc = 0.f, vf_acc = 0.f;
    const short8 zfrag = {0,0,0,0,0,0,0,0};

    for (int n = 0; n < NSTEPS; ++n) {
        const float t0 = (float)n * dt;
        for (int sg = 0; sg < 6; ++sg) {
            const float t_eff = 1.0f - (t0 + Ctab[sg]*dt);

            // ---- layer 1 + A-column build (reads own-wave xs; no barrier) ----
            {
                float pre = b1u + t_eff * w1t;
                #pragma unroll
                for (int q = 0; q < 8; ++q) {
                    f32x4 xq = *(const f32x4*)&xs_s[w][q*4];   // own-wave broadcast
                    unsigned p0 = w1p[2*q], p1 = w1p[2*q+1];
                    pre += xq[0]*bf_lo(p0) + xq[1]*bf_hi(p0)
                         + xq[2]*bf_lo(p1) + xq[3]*bf_hi(p1);
                }
                const float h1 = fast_tanh(pre);
                const float s1 = 1.f - h1*h1;
                #pragma unroll
                for (int q = 0; q < 16; ++q) {
                    unsigned p = w1p[q];
                    *(short*)SWZ(LAc, 2*q,   2*tid) = f2bf(bf_lo(p)*s1);
                    *(short*)SWZ(LAc, 2*q+1, 2*tid) = f2bf(bf_hi(p)*s1);
                }
                ((short*)LAA)[32*256 + tid] = f2bf(h1);  // row32 (swz==0)
            }
            __syncthreads();   // B1: A ready

            // ---- T^T GEMM: j = w*64+m*16+g*4+r, i = nt*16+c ----
            f32x4 acc[4][3];
            #pragma unroll
            for (int m = 0; m < 4; ++m)
                #pragma unroll
                for (int q = 0; q < 3; ++q) acc[m][q] = (f32x4){0.f,0.f,0.f,0.f};
            #pragma unroll
            for (int kk = 0; kk < 8; ++kk) {
                const int bo = kk*64 + g*16;
                short8 fA0 = *(const short8*)(LAc + (( 0 + c) << 9) + (bo ^ swc));
                short8 fA1 = *(const short8*)(LAc + ((16 + c) << 9) + (bo ^ swc));
                short8 fA2 = zfrag;                       // i=32 col: h1 only at c==0
                if (c == 0) fA2 = *(const short8*)(LAc + (32 << 9) + bo);
                #pragma unroll
                for (int m = 0; m < 4; ++m) {
                    acc[m][0] = __builtin_amdgcn_mfma_f32_16x16x32_bf16(w2f[m][kk], fA0, acc[m][0], 0,0,0);
                    acc[m][1] = __builtin_amdgcn_mfma_f32_16x16x32_bf16(w2f[m][kk], fA1, acc[m][1], 0,0,0);
                    acc[m][2] = __builtin_amdgcn_mfma_f32_16x16x32_bf16(w2f[m][kk], fA2, acc[m][2], 0,0,0);
                }
            }
            // h2_pre exchange + activation (all own-wave LDS, in-order)
            if (c == 0) {
                #pragma unroll
                for (int m = 0; m < 4; ++m)
                    *(f32x4*)&h2pre_s[w*64 + m*16 + g*4] = acc[m][2];
            }
            const float h2 = fast_tanh(h2pre_s[tid] + b2u);
            s2_s[tid] = 1.f - h2*h2;
            ((short*)LTs)[32*256 + tid] = f2bf(h2);       // row32 := h2
            // ---- Ts^T store: LTs[i][j] = T^T[j][i]*s2[j] ----
            #pragma unroll
            for (int m = 0; m < 4; ++m) {
                const int j0 = w*64 + m*16 + g*4;
                f32x4 s2q = *(const f32x4*)&s2_s[j0];     // own-wave broadcast
                #pragma unroll
                for (int q = 0; q < 2; ++q) {
                    f32x4 v = acc[m][q] * s2q;
                    short4v p;
                    p[0] = f2bf(v[0]); p[1] = f2bf(v[1]); p[2] = f2bf(v[2]); p[3] = f2bf(v[3]);
                    *(short4v*)SWZ(LTc, q*16 + c, 2*j0) = p;
                }
            }
            __syncthreads();   // B2: Ts ready

            // ---- J-phase: 2 vf tiles (all waves, redundant) + 1 J tile (exclusive) ----
            f32x4 jva = (f32x4){0,0,0,0}, jvb = (f32x4){0,0,0,0}, jj = (f32x4){0,0,0,0};
            #pragma unroll
            for (int kk = 0; kk < 8; ++kk) {
                const int bo = kk*64 + g*16;
                short8 w3f0 = W3L[kk*64 + l];         // mt=0
                short8 w3f1 = W3L[(8+kk)*64 + l];     // mt=1
                short8 h2f = zfrag;
                if (c == 0) h2f = *(const short8*)(LTc + (32 << 9) + bo);
                jva = __builtin_amdgcn_mfma_f32_16x16x32_bf16(w3f0, h2f, jva, 0,0,0);
                jvb = __builtin_amdgcn_mfma_f32_16x16x32_bf16(w3f1, h2f, jvb, 0,0,0);
                short8 bJ = *(const short8*)(LTc + ((ntJ*16 + c) << 9) + (bo ^ swc));
                jj = __builtin_amdgcn_mfma_f32_16x16x32_bf16((mtJ == 0) ? w3f0 : w3f1, bJ, jj, 0,0,0);
            }

            const float wB = dt * Btab[sg];
            // ---- vf + per-wave ODE state update (same-wave, no barrier) ----
            if (c == 0) {
                f32x4 dxa, dxb;
                dxa[0] = -(jva[0]+b3a[0]); dxa[1] = -(jva[1]+b3a[1]);
                dxa[2] = -(jva[2]+b3a[2]); dxa[3] = -(jva[3]+b3a[3]);
                dxb[0] = -(jvb[0]+b3b[0]); dxb[1] = -(jvb[1]+b3b[1]);
                dxb[2] = -(jvb[2]+b3b[2]); dxb[3] = -(jvb[3]+b3b[3]);
                *(f32x4*)&ksb[w][sg][g*4]      = dxa;
                *(f32x4*)&ksb[w][sg][16 + g*4] = dxb;
                if (w == 3)   // count vf once
                    vf_acc += wB * (dxa[0]*dxa[0]+dxa[1]*dxa[1]+dxa[2]*dxa[2]+dxa[3]*dxa[3]
                                  + dxb[0]*dxb[0]+dxb[1]*dxb[1]+dxb[2]*dxb[2]+dxb[3]*dxb[3]);
            }
            if (l < ND) {
                if (sg < 5) {
                    float v = xc_s[w][l];
                    for (int q = 0; q <= sg; ++q) v += dt * Atab[sg+1][q] * ksb[w][q][l];
                    xs_s[w][l] = v;
                } else {
                    float v = xc_s[w][l];
                    #pragma unroll
                    for (int q = 0; q < 6; ++q) v += dt * Btab[q] * ksb[w][q][l];
                    xc_s[w][l] = v;
                    xs_s[w][l] = v;
                }
            }
            // ---- frob / trace (exclusive J tile) ----
            fr_acc += wB * (jj[0]*jj[0]+jj[1]*jj[1]+jj[2]*jj[2]+jj[3]*jj[3]);
            if (mtJ == ntJ) {
                const int dd = c - g*4;
                if (dd >= 0 && dd < 4) {
                    float da = (dd==0)?jj[0]:(dd==1)?jj[1]:(dd==2)?jj[2]:jj[3];
                    ld_acc -= wB * da;
                }
            }
        }
    }

    // ---- final reduction of the three integrals ----
    float fr = fr_acc, ld = ld_acc, vf = vf_acc;
    #pragma unroll
    for (int off = 32; off > 0; off >>= 1) {
        fr += __shfl_down(fr, off, 64);
        ld += __shfl_down(ld, off, 64);
        vf += __shfl_down(vf, off, 64);
    }
    if (l == 0) { red[w][0] = fr; red[w][1] = ld; red[w][2] = vf; }
    __syncthreads();
    if (tid == 0) {
        float a = 0.f, b = 0.f, cq = 0.f;
        #pragma unroll
        for (int q = 0; q < 4; ++q) { a += red[q][0]; b += red[q][1]; cq += red[q][2]; }
        out[bid*35 + 32] = b;    // log_det = -∫tr
        out[bid*35 + 33] = cq;   // ∫|dxdt|^2
        out[bid*35 + 34] = a;    // ∫sum(J*J)
    }
    if (w == 3 && l < ND) out[bid*35 + l] = xc_s[3][l];
}

extern "C" void kernel_launch(void* const* d_in, const int* in_sizes, int n_in,
                              void* d_out, int out_size, void* d_ws, size_t ws_size,
                              hipStream_t stream) {
    const float* x  = (const float*)d_in[0];
    const float* W1 = (const float*)d_in[1];
    const float* b1 = (const float*)d_in[2];
    const float* W2 = (const float*)d_in[3];
    const float* b2 = (const float*)d_in[4];
    const float* W3 = (const float*)d_in[5];
    const float* b3 = (const float*)d_in[6];
    float* outp = (float*)d_out;
    hipLaunchKernelGGL(prep_kernel, dim3(1), dim3(256), 0, stream,
                       W3, (short8*)d_ws);
    hipLaunchKernelGGL(node_kernel, dim3(NB), dim3(256), 0, stream,
                       x, W1, b1, W2, b2, W3, b3, (const short8*)d_ws, outp);
}

// Round 6
// 212.254 us; speedup vs baseline: 1.6127x; 1.2750x over previous
//
#include <hip/hip_runtime.h>

#define NB 512
#define ND 32
#define NH 256
#define NSTEPS 8

typedef __attribute__((ext_vector_type(8))) short short8;
typedef __attribute__((ext_vector_type(4))) short short4v;
typedef __attribute__((ext_vector_type(4))) float f32x4;

__device__ __constant__ float Atab[6][5] = {
    {0.f, 0.f, 0.f, 0.f, 0.f},
    {0.2f, 0.f, 0.f, 0.f, 0.f},
    {3.f/40.f, 9.f/40.f, 0.f, 0.f, 0.f},
    {44.f/45.f, -56.f/15.f, 32.f/9.f, 0.f, 0.f},
    {19372.f/6561.f, -25360.f/2187.f, 64448.f/6561.f, -212.f/729.f, 0.f},
    {9017.f/3168.f, -355.f/33.f, 46732.f/5247.f, 49.f/176.f, -5103.f/18656.f}
};
__device__ __constant__ float Btab[6] = {
    35.f/384.f, 0.f, 500.f/1113.f, 125.f/192.f, -2187.f/6784.f, 11.f/84.f
};
__device__ __constant__ float Ctab[6] = {0.f, 0.2f, 0.3f, 0.8f, 8.f/9.f, 1.f};

static __device__ __forceinline__ short f2bf(float f){
    __bf16 h = (__bf16)f;
    return __builtin_bit_cast(short, h);
}
static __device__ __forceinline__ float bf_lo(unsigned p){
    return __builtin_bit_cast(float, p << 16);
}
static __device__ __forceinline__ float bf_hi(unsigned p){
    return __builtin_bit_cast(float, p & 0xffff0000u);
}
static __device__ __forceinline__ float fast_tanh(float x){
    float e = __expf(2.f * x);
    return 1.f - 2.f / (e + 1.f);
}

// XOR-swizzled LDS addressing: row stride 512B, byte ^= (row&7)<<4.
#define SWZ(base, row, byte) ((base) + ((row) << 9) + ((byte) ^ (((row) & 7) << 4)))

// ---- prep: fragment-ordered bf16 W3 into ws ----
// frag(mt,kk), lane l: short8 of W3[kk*32+g*8+e][mt*16+c], at ws[(mt*8+kk)*64+l]
extern "C" __global__ void prep_kernel(const float* __restrict__ W3,
                                       short8* __restrict__ ws)
{
    const int tid = threadIdx.x;
    #pragma unroll
    for (int r = 0; r < 4; ++r) {
        const int idx = r*256 + tid;          // 0..1023
        const int l  = idx & 63;
        const int kk = (idx >> 6) & 7;
        const int mt = idx >> 9;
        const int g = (l >> 4) & 3, c = l & 15;
        short8 v;
        #pragma unroll
        for (int e = 0; e < 8; ++e)
            v[e] = f2bf(W3[(kk*32 + g*8 + e)*ND + mt*16 + c]);
        ws[idx] = v;
    }
}

// One block per batch element; 4 waves (256 threads); 2 blocks/CU.
// T^T GEMM (two passes): M=j(256, 4 Mtiles/wave), N=i, K=256.
// W2 fragments register-resident; W1 packed in LDS; W3 fragments in LDS;
// per-wave private ODE state (vf computed redundantly by all waves).
extern "C" __global__ void __launch_bounds__(256, 2)
node_kernel(const float* __restrict__ x_in,
            const float* __restrict__ W1, const float* __restrict__ b1,
            const float* __restrict__ W2, const float* __restrict__ b2,
            const float* __restrict__ W3, const float* __restrict__ b3,
            const short8* __restrict__ w3ws,
            float* __restrict__ out)
{
    __shared__ __align__(16) short LAA[33*256];   // A^T rows 0..31 + row32 = h1 (swizzled)
    __shared__ __align__(16) short LTs[33*256];   // Ts^T rows 0..31 + row32 = h2 (swizzled)
    __shared__ __align__(16) short8 W3L[16*64];   // fragment-ordered W3 (16 KB)
    __shared__ __align__(16) unsigned LW1[16*256];// packed bf16-pair W1 columns (16 KB)
    __shared__ __align__(16) float h2pre_s[NH];
    __shared__ __align__(16) float s2_s[NH];
    __shared__ __align__(16) float xs_s[4][ND];   // per-wave private
    __shared__ __align__(16) float xc_s[4][ND];   // per-wave private
    __shared__ __align__(16) float ksb[4][6][ND]; // per-wave private
    __shared__ float red[4][3];

    const int bid = blockIdx.x;
    const int tid = threadIdx.x;
    const int w = tid >> 6;        // wave id
    const int l = tid & 63;        // lane
    const int g = (tid >> 4) & 3;  // lane group
    const int c = tid & 15;        // lane&15

    char* LAc = (char*)LAA;
    char* LTc = (char*)LTs;
    const int swc = (c & 7) << 4;  // read-side swizzle

    // ---- one-time: W2 fragments into registers ----
    // frag (m,kk): value W2[kk*32+g*8+e][w*64+m*16+c]
    short8 w2f[4][8];
    #pragma unroll
    for (int m = 0; m < 4; ++m) {
        const int j = w*64 + m*16 + c;
        #pragma unroll
        for (int kk = 0; kk < 8; ++kk) {
            const int k0 = kk*32 + g*8;
            short8 f;
            #pragma unroll
            for (int e = 0; e < 8; ++e) f[e] = f2bf(W2[(k0+e)*NH + j]);
            w2f[m][kk] = f;
        }
    }
    // ---- one-time: W1 column tid packed bf16 into LDS; scalars in regs ----
    float w1t, b1u, b2u;
    {
        #pragma unroll
        for (int q = 0; q < 16; ++q) {
            unsigned lo = (unsigned)(unsigned short)f2bf(W1[(2*q)*NH + tid]);
            unsigned hi = (unsigned)(unsigned short)f2bf(W1[(2*q+1)*NH + tid]);
            LW1[q*256 + tid] = lo | (hi << 16);
        }
        w1t = W1[32*NH + tid];
        b1u = b1[tid];
        b2u = b2[tid];
    }
    // ---- one-time: b3 quads (used at c==0 lanes) ----
    const f32x4 b3a = *(const f32x4*)(b3 + g*4);
    const f32x4 b3b = *(const f32x4*)(b3 + 16 + g*4);
    // ---- one-time: W3 fragments global->LDS (coalesced b128) ----
    #pragma unroll
    for (int r = 0; r < 4; ++r) W3L[r*256 + tid] = w3ws[r*256 + tid];
    // ---- J-phase: each wave owns one J tile ----
    const int mtJ = w >> 1, ntJ = w & 1;

    // ---- init per-wave ODE state ----
    if (l < ND) {
        const float xv = x_in[bid*ND + l];
        xc_s[w][l] = xv;
        xs_s[w][l] = xv;
    }
    __syncthreads();

    const float dt = 0.125f;
    float fr_acc = 0.f, ld_acc = 0.f, vf_acc = 0.f;
    const short8 zfrag = {0,0,0,0,0,0,0,0};

    for (int n = 0; n < NSTEPS; ++n) {
        const float t0 = (float)n * dt;
        for (int sg = 0; sg < 6; ++sg) {
            const float t_eff = 1.0f - (t0 + Ctab[sg]*dt);

            // ---- layer 1 + A-column build (own-wave xs; W1 from LDS) ----
            {
                float pre = b1u + t_eff * w1t;
                #pragma unroll
                for (int q = 0; q < 8; ++q) {
                    f32x4 xq = *(const f32x4*)&xs_s[w][q*4];   // own-wave broadcast
                    unsigned p0 = LW1[(2*q)*256 + tid];
                    unsigned p1 = LW1[(2*q+1)*256 + tid];
                    pre += xq[0]*bf_lo(p0) + xq[1]*bf_hi(p0)
                         + xq[2]*bf_lo(p1) + xq[3]*bf_hi(p1);
                }
                const float h1 = fast_tanh(pre);
                const float s1 = 1.f - h1*h1;
                #pragma unroll
                for (int q = 0; q < 16; ++q) {
                    unsigned p = LW1[q*256 + tid];
                    *(short*)SWZ(LAc, 2*q,   2*tid) = f2bf(bf_lo(p)*s1);
                    *(short*)SWZ(LAc, 2*q+1, 2*tid) = f2bf(bf_hi(p)*s1);
                }
                ((short*)LAA)[32*256 + tid] = f2bf(h1);  // row32 (swz==0)
            }
            __syncthreads();   // B1: A ready

            // ---- T^T pass 1: h1 column tile (nt=2) -> h2pre ----
            {
                f32x4 acc2[4];
                #pragma unroll
                for (int m = 0; m < 4; ++m) acc2[m] = (f32x4){0.f,0.f,0.f,0.f};
                #pragma unroll
                for (int kk = 0; kk < 8; ++kk) {
                    const int bo = kk*64 + g*16;
                    short8 fA2 = zfrag;                   // i=32 col: h1 only at c==0
                    if (c == 0) fA2 = *(const short8*)(LAc + (32 << 9) + bo);
                    #pragma unroll
                    for (int m = 0; m < 4; ++m)
                        acc2[m] = __builtin_amdgcn_mfma_f32_16x16x32_bf16(w2f[m][kk], fA2, acc2[m], 0,0,0);
                }
                if (c == 0) {
                    #pragma unroll
                    for (int m = 0; m < 4; ++m)
                        *(f32x4*)&h2pre_s[w*64 + m*16 + g*4] = acc2[m];
                }
            }
            const float h2 = fast_tanh(h2pre_s[tid] + b2u);   // own-wave LDS, in-order
            s2_s[tid] = 1.f - h2*h2;
            ((short*)LTs)[32*256 + tid] = f2bf(h2);           // row32 := h2

            // ---- T^T pass 2: tangent tiles (nt=0,1), scale & store ----
            {
                f32x4 accT[4][2];
                #pragma unroll
                for (int m = 0; m < 4; ++m) {
                    accT[m][0] = (f32x4){0.f,0.f,0.f,0.f};
                    accT[m][1] = (f32x4){0.f,0.f,0.f,0.f};
                }
                #pragma unroll
                for (int kk = 0; kk < 8; ++kk) {
                    const int bo = kk*64 + g*16;
                    short8 fA0 = *(const short8*)(LAc + (( 0 + c) << 9) + (bo ^ swc));
                    short8 fA1 = *(const short8*)(LAc + ((16 + c) << 9) + (bo ^ swc));
                    #pragma unroll
                    for (int m = 0; m < 4; ++m) {
                        accT[m][0] = __builtin_amdgcn_mfma_f32_16x16x32_bf16(w2f[m][kk], fA0, accT[m][0], 0,0,0);
                        accT[m][1] = __builtin_amdgcn_mfma_f32_16x16x32_bf16(w2f[m][kk], fA1, accT[m][1], 0,0,0);
                    }
                }
                #pragma unroll
                for (int m = 0; m < 4; ++m) {
                    const int j0 = w*64 + m*16 + g*4;
                    f32x4 s2q = *(const f32x4*)&s2_s[j0];     // own-wave broadcast
                    #pragma unroll
                    for (int q = 0; q < 2; ++q) {
                        f32x4 v = accT[m][q] * s2q;
                        short4v p;
                        p[0] = f2bf(v[0]); p[1] = f2bf(v[1]); p[2] = f2bf(v[2]); p[3] = f2bf(v[3]);
                        *(short4v*)SWZ(LTc, q*16 + c, 2*j0) = p;
                    }
                }
            }
            __syncthreads();   // B2: Ts ready

            // ---- J-phase: 2 vf tiles (all waves, redundant) + 1 J tile (exclusive) ----
            f32x4 jva = (f32x4){0,0,0,0}, jvb = (f32x4){0,0,0,0}, jj = (f32x4){0,0,0,0};
            #pragma unroll
            for (int kk = 0; kk < 8; ++kk) {
                const int bo = kk*64 + g*16;
                short8 w3f0 = W3L[kk*64 + l];         // mt=0
                short8 w3f1 = W3L[(8+kk)*64 + l];     // mt=1
                short8 h2f = zfrag;
                if (c == 0) h2f = *(const short8*)(LTc + (32 << 9) + bo);
                jva = __builtin_amdgcn_mfma_f32_16x16x32_bf16(w3f0, h2f, jva, 0,0,0);
                jvb = __builtin_amdgcn_mfma_f32_16x16x32_bf16(w3f1, h2f, jvb, 0,0,0);
                short8 bJ = *(const short8*)(LTc + ((ntJ*16 + c) << 9) + (bo ^ swc));
                jj = __builtin_amdgcn_mfma_f32_16x16x32_bf16((mtJ == 0) ? w3f0 : w3f1, bJ, jj, 0,0,0);
            }

            const float wB = dt * Btab[sg];
            // ---- vf + per-wave ODE state update (same-wave, no barrier) ----
            if (c == 0) {
                f32x4 dxa, dxb;
                dxa[0] = -(jva[0]+b3a[0]); dxa[1] = -(jva[1]+b3a[1]);
                dxa[2] = -(jva[2]+b3a[2]); dxa[3] = -(jva[3]+b3a[3]);
                dxb[0] = -(jvb[0]+b3b[0]); dxb[1] = -(jvb[1]+b3b[1]);
                dxb[2] = -(jvb[2]+b3b[2]); dxb[3] = -(jvb[3]+b3b[3]);
                *(f32x4*)&ksb[w][sg][g*4]      = dxa;
                *(f32x4*)&ksb[w][sg][16 + g*4] = dxb;
                if (w == 3)   // count vf once
                    vf_acc += wB * (dxa[0]*dxa[0]+dxa[1]*dxa[1]+dxa[2]*dxa[2]+dxa[3]*dxa[3]
                                  + dxb[0]*dxb[0]+dxb[1]*dxb[1]+dxb[2]*dxb[2]+dxb[3]*dxb[3]);
            }
            if (l < ND) {
                if (sg < 5) {
                    float v = xc_s[w][l];
                    for (int q = 0; q <= sg; ++q) v += dt * Atab[sg+1][q] * ksb[w][q][l];
                    xs_s[w][l] = v;
                } else {
                    float v = xc_s[w][l];
                    #pragma unroll
                    for (int q = 0; q < 6; ++q) v += dt * Btab[q] * ksb[w][q][l];
                    xc_s[w][l] = v;
                    xs_s[w][l] = v;
                }
            }
            // ---- frob / trace (exclusive J tile) ----
            fr_acc += wB * (jj[0]*jj[0]+jj[1]*jj[1]+jj[2]*jj[2]+jj[3]*jj[3]);
            if (mtJ == ntJ) {
                const int dd = c - g*4;
                if (dd >= 0 && dd < 4) {
                    float da = (dd==0)?jj[0]:(dd==1)?jj[1]:(dd==2)?jj[2]:jj[3];
                    ld_acc -= wB * da;
                }
            }
        }
    }

    // ---- final reduction of the three integrals ----
    float fr = fr_acc, ld = ld_acc, vf = vf_acc;
    #pragma unroll
    for (int off = 32; off > 0; off >>= 1) {
        fr += __shfl_down(fr, off, 64);
        ld += __shfl_down(ld, off, 64);
        vf += __shfl_down(vf, off, 64);
    }
    if (l == 0) { red[w][0] = fr; red[w][1] = ld; red[w][2] = vf; }
    __syncthreads();
    if (tid == 0) {
        float a = 0.f, b = 0.f, cq = 0.f;
        #pragma unroll
        for (int q = 0; q < 4; ++q) { a += red[q][0]; b += red[q][1]; cq += red[q][2]; }
        out[bid*35 + 32] = b;    // log_det = -∫tr
        out[bid*35 + 33] = cq;   // ∫|dxdt|^2
        out[bid*35 + 34] = a;    // ∫sum(J*J)
    }
    if (w == 3 && l < ND) out[bid*35 + l] = xc_s[3][l];
}

extern "C" void kernel_launch(void* const* d_in, const int* in_sizes, int n_in,
                              void* d_out, int out_size, void* d_ws, size_t ws_size,
                              hipStream_t stream) {
    const float* x  = (const float*)d_in[0];
    const float* W1 = (const float*)d_in[1];
    const float* b1 = (const float*)d_in[2];
    const float* W2 = (const float*)d_in[3];
    const float* b2 = (const float*)d_in[4];
    const float* W3 = (const float*)d_in[5];
    const float* b3 = (const float*)d_in[6];
    float* outp = (float*)d_out;
    hipLaunchKernelGGL(prep_kernel, dim3(1), dim3(256), 0, stream,
                       W3, (short8*)d_ws);
    hipLaunchKernelGGL(node_kernel, dim3(NB), dim3(256), 0, stream,
                       x, W1, b1, W2, b2, W3, b3, (const short8*)d_ws, outp);
}